// Round 5
// baseline (5916.807 us; speedup 1.0000x reference)
//
#include <hip/hip_runtime.h>
#include <math.h>

#define BB 32
#define TT 20
#define VV 30000
#define NBLK 256   // k_rec grid: 1 block/CU, co-resident by capacity

typedef short short8 __attribute__((ext_vector_type(8)));
typedef unsigned short ushort8 __attribute__((ext_vector_type(8)));
typedef float floatx4 __attribute__((ext_vector_type(4)));

__device__ __forceinline__ float dot4(float4 a, float4 b) {
  return a.x*b.x + a.y*b.y + a.z*b.z + a.w*b.w;
}

__device__ __forceinline__ unsigned short f2bf(float f) {
  unsigned int u = __builtin_bit_cast(unsigned int, f);
  u = u + 0x7fffu + ((u >> 16) & 1u);   // RNE
  return (unsigned short)(u >> 16);
}

// ---------------- barrier state init ----------------
__global__ void k_zero(unsigned* __restrict__ bar)
{
  if (threadIdx.x < 2) bar[threadIdx.x] = 0u;
}

// ---------------- fp32 -> bf16 bulk convert (8 elems/thread) ----------------
__global__ __launch_bounds__(256) void k_cvt(const float* __restrict__ src,
                                             unsigned short* __restrict__ dst, int n8)
{
  int i = blockIdx.x*256 + threadIdx.x;
  if (i >= n8) return;
  const float4* s = ((const float4*)src) + (size_t)i*2;
  float4 a = s[0], b = s[1];
  ushort8 v;
  v[0]=f2bf(a.x); v[1]=f2bf(a.y); v[2]=f2bf(a.z); v[3]=f2bf(a.w);
  v[4]=f2bf(b.x); v[5]=f2bf(b.y); v[6]=f2bf(b.z); v[7]=f2bf(b.w);
  ((ushort8*)dst)[i] = v;
}

// ---------------- prep: attr_cat gather (fp32) + teacher-forced embeddings (bf16) ----------------
__global__ __launch_bounds__(256) void k_prep(const int* __restrict__ user, const int* __restrict__ product,
    const int* __restrict__ rating, const int* __restrict__ trg,
    const float* __restrict__ embed, const float* __restrict__ user_w,
    const float* __restrict__ product_w, const float* __restrict__ rating_w,
    float* __restrict__ attr_cat, unsigned short* __restrict__ xs_bf)
{
  int i = blockIdx.x*256 + threadIdx.x;
  if (i < BB*1536) {
    int b = i / 1536, j = i - b*1536;
    float v;
    if (j < 512)       v = user_w[(size_t)user[b]*512 + j];
    else if (j < 1024) v = product_w[(size_t)product[b]*512 + (j-512)];
    else               v = rating_w[(size_t)rating[b]*512 + (j-1024)];
    attr_cat[i] = v;
  }
  int i2 = i - BB*1536;
  if (i2 >= 0 && i2 < TT*BB*512) {
    int t = i2 >> 14;
    int r = i2 & 16383;
    int b = r >> 9, e = r & 511;
    int tok = (t == 0) ? 1 : trg[b*TT + (t-1)];
    xs_bf[i2] = f2bf(embed[(size_t)tok*512 + e]);
  }
}

// ---------------- encoder init states ----------------
__global__ __launch_bounds__(256) void k_enc(const float* __restrict__ attr_cat, const float* __restrict__ enc_w,
    const float* __restrict__ enc_b, float* __restrict__ h0, float* __restrict__ h1, float* __restrict__ ctx0)
{
  int i = blockIdx.x*256 + threadIdx.x;
  int b = i & 31, j = i >> 5;
  const float4* a = (const float4*)(attr_cat + b*1536);
  const float4* w = (const float4*)(enc_w + (size_t)j*1536);
  float acc = 0.f;
  #pragma unroll 8
  for (int k = 0; k < 384; k++) acc += dot4(a[k], w[k]);
  acc += enc_b[j];
  float v = acc > 0.f ? acc : 0.01f*acc;
  if (j < 512) h0[b*512 + j] = v;
  else { h1[b*512 + (j-512)] = v; ctx0[b*512 + (j-512)] = v; }
}

// ---------------- proj_key ----------------
__global__ __launch_bounds__(256) void k_key(const float* __restrict__ attr_cat, const float* __restrict__ key_w,
    float* __restrict__ proj_key)
{
  int i = blockIdx.x*256 + threadIdx.x;
  int b = i & 31, j = i >> 5;
  int k3 = j >> 9, h = j & 511;
  const float4* a = (const float4*)(attr_cat + b*1536 + k3*512);
  const float4* w = (const float4*)(key_w + (size_t)h*512);
  float acc = 0.f;
  #pragma unroll 8
  for (int k = 0; k < 128; k++) acc += dot4(a[k], w[k]);
  proj_key[(b*3 + k3)*512 + h] = acc;
}

// ---------------- gx MFMA: gx[640][1536] = xs_bf[640,512] @ w_ih0[:,0:512].T + b_ih0 ----------------
// Exact r2 k_gen structure (stride-64 LDS); B row stride 1024 (cols 0:512 of w_ih0).
__global__ __launch_bounds__(256) void k_gx_mfma(const unsigned short* __restrict__ Abf,
    const unsigned short* __restrict__ Bbf, const float* __restrict__ bias, float* __restrict__ out)
{
  __shared__ unsigned short As[128*64];
  __shared__ unsigned short Bs[128*64];
  int tid = threadIdx.x;
  int ntile = blockIdx.x, mtile = blockIdx.y;
  int lane = tid & 63, wave = tid >> 6;
  int quad = lane >> 4, l15 = lane & 15;
  int wm = (wave >> 1) * 64, wn = (wave & 1) * 64;
  int m0 = mtile * 128, n0 = ntile * 128;
  floatx4 acc[4][4] = {};
  for (int kt = 0; kt < 8; kt++) {
    __syncthreads();
    #pragma unroll
    for (int c = 0; c < 4; c++) {
      int f = c*256 + tid;
      int row = f >> 3, k8 = (f & 7) * 8;
      ((short8*)As)[f] = *(const short8*)(Abf + (size_t)(m0 + row)*512 + kt*64 + k8);
      ((short8*)Bs)[f] = *(const short8*)(Bbf + (size_t)(n0 + row)*1024 + kt*64 + k8);
    }
    __syncthreads();
    #pragma unroll
    for (int ks = 0; ks < 2; ks++) {
      short8 af[4], bfr[4];
      #pragma unroll
      for (int i = 0; i < 4; i++)
        af[i] = *(const short8*)&As[(wm + i*16 + l15)*64 + ks*32 + quad*8];
      #pragma unroll
      for (int j = 0; j < 4; j++)
        bfr[j] = *(const short8*)&Bs[(wn + j*16 + l15)*64 + ks*32 + quad*8];
      #pragma unroll
      for (int i = 0; i < 4; i++)
        #pragma unroll
        for (int j = 0; j < 4; j++)
          acc[i][j] = __builtin_amdgcn_mfma_f32_16x16x32_bf16(af[i], bfr[j], acc[i][j], 0, 0, 0);
    }
  }
  #pragma unroll
  for (int i = 0; i < 4; i++) {
    int mbase = m0 + wm + i*16 + quad*4;
    #pragma unroll
    for (int j = 0; j < 4; j++) {
      int n = n0 + wn + j*16 + l15;
      float bv = bias[n];
      #pragma unroll
      for (int r = 0; r < 4; r++)
        out[(size_t)(mbase + r)*1536 + n] = acc[i][j][r] + bv;
    }
  }
}

// ---------------- persistent recurrence: all 20 steps in one launch ----------------
// grid barrier: sense-reversing, plain HIP atomics (device-scope on CDNA)
__device__ __forceinline__ void gsync(unsigned* bar)
{
  __syncthreads();
  if (threadIdx.x == 0) {
    __threadfence();                          // release
    unsigned g = atomicOr(bar + 1, 0u);       // read generation (device-scope RMW)
    if (atomicAdd(bar, 1u) == NBLK - 1u) {
      atomicAnd(bar, 0u);                     // reset arrival count
      __threadfence();
      atomicAdd(bar + 1, 1u);                 // bump generation
    } else {
      while (atomicOr(bar + 1, 0u) == g)
        __builtin_amdgcn_s_sleep(4);
    }
    __threadfence();                          // acquire
  }
  __syncthreads();
}

__global__ __launch_bounds__(256) void k_rec(
    const float* __restrict__ gx_all, const float* __restrict__ wih0c,
    const float* __restrict__ whh0, const float* __restrict__ bhh0,
    const float* __restrict__ wih1, const float* __restrict__ bih1,
    const float* __restrict__ whh1, const float* __restrict__ bhh1,
    const float* __restrict__ query_w, const float* __restrict__ energy_w,
    const float* __restrict__ ctx_w, const float* __restrict__ ctx_b,
    const float* __restrict__ proj_key, const float* __restrict__ attr_cat,
    float* __restrict__ h0buf, float* __restrict__ h1buf, float* __restrict__ ctx_all,
    unsigned* __restrict__ bar)
{
  __shared__ float h1s[512];
  __shared__ float q[512];
  __shared__ float cv[512];
  __shared__ float red3[768];
  __shared__ float al[3];
  int tid = threadIdx.x, blk = blockIdx.x;
  int ks = tid & 7;          // 8-way K split (64 floats each)
  int b  = tid >> 3;         // batch 0..31

  for (int t = 0; t < TT; t++) {
    const float* ctx_t = ctx_all + t*BB*512;
    const float* h0_in = h0buf + (t & 1)*BB*512;
    float*       h0_out= h0buf + ((t+1) & 1)*BB*512;
    const float* h1_in = h1buf + (t & 1)*BB*512;
    float*       h1_out= h1buf + ((t+1) & 1)*BB*512;

    // ---- Stage A: gru0 (x = ctx_t; embedding x-part precomputed in gx_all) ----
    {
      const float4* xv = (const float4*)(ctx_t + b*512 + ks*64);
      const float4* hv = (const float4*)(h0_in + b*512 + ks*64);
      for (int hh = 0; hh < 2; hh++) {
        int h = blk*2 + hh;
        float acc[6];
        #pragma unroll
        for (int g = 0; g < 3; g++) {
          const float4* wiv = (const float4*)(wih0c + (size_t)(g*512 + h)*1024 + ks*64);
          const float4* whv = (const float4*)(whh0 + (size_t)(g*512 + h)*512 + ks*64);
          float ai = 0.f, ah = 0.f;
          #pragma unroll
          for (int k = 0; k < 16; k++) { ai += dot4(xv[k], wiv[k]); ah += dot4(hv[k], whv[k]); }
          acc[g] = ai; acc[3+g] = ah;
        }
        #pragma unroll
        for (int d = 1; d < 8; d <<= 1) {
          #pragma unroll
          for (int j = 0; j < 6; j++) acc[j] += __shfl_xor(acc[j], d);
        }
        if (ks == 0) {
          const float* gxrow = gx_all + (size_t)t*BB*1536;
          float ir = acc[0] + gxrow[b*1536 + h];
          float iz = acc[1] + gxrow[b*1536 + 512 + h];
          float inn= acc[2] + gxrow[b*1536 + 1024 + h];
          float hr = acc[3] + bhh0[h];
          float hz = acc[4] + bhh0[512+h];
          float hn = acc[5] + bhh0[1024+h];
          float r = 1.f/(1.f + expf(-(ir+hr)));
          float z = 1.f/(1.f + expf(-(iz+hz)));
          float n = tanhf(inn + r*hn);
          h0_out[b*512+h] = (1.f - z)*n + z*h0_in[b*512+h];
        }
      }
    }
    gsync(bar);

    // ---- Stage B: gru1 (x = h0_out) ----
    {
      const float4* xv = (const float4*)(h0_out + b*512 + ks*64);
      const float4* hv = (const float4*)(h1_in + b*512 + ks*64);
      for (int hh = 0; hh < 2; hh++) {
        int h = blk*2 + hh;
        float acc[6];
        #pragma unroll
        for (int g = 0; g < 3; g++) {
          const float4* wiv = (const float4*)(wih1 + (size_t)(g*512 + h)*512 + ks*64);
          const float4* whv = (const float4*)(whh1 + (size_t)(g*512 + h)*512 + ks*64);
          float ai = 0.f, ah = 0.f;
          #pragma unroll
          for (int k = 0; k < 16; k++) { ai += dot4(xv[k], wiv[k]); ah += dot4(hv[k], whv[k]); }
          acc[g] = ai; acc[3+g] = ah;
        }
        #pragma unroll
        for (int d = 1; d < 8; d <<= 1) {
          #pragma unroll
          for (int j = 0; j < 6; j++) acc[j] += __shfl_xor(acc[j], d);
        }
        if (ks == 0) {
          float ir = acc[0] + bih1[h];
          float iz = acc[1] + bih1[512+h];
          float inn= acc[2] + bih1[1024+h];
          float hr = acc[3] + bhh1[h];
          float hz = acc[4] + bhh1[512+h];
          float hn = acc[5] + bhh1[1024+h];
          float r = 1.f/(1.f + expf(-(ir+hr)));
          float z = 1.f/(1.f + expf(-(iz+hz)));
          float n = tanhf(inn + r*hn);
          h1_out[b*512+h] = (1.f - z)*n + z*h1_in[b*512+h];
        }
      }
    }
    gsync(bar);

    // ---- Stage C: q + attention + ctx projection (blocks 0..31, one per batch) ----
    if (blk < BB) {
      int bb = blk;
      for (int h = tid; h < 512; h += 256) h1s[h] = h1_out[bb*512 + h];
      __syncthreads();
      const float4* xv = (const float4*)h1s;
      for (int h = tid; h < 512; h += 256) {
        const float4* w = (const float4*)(query_w + (size_t)h*512);
        float a = 0.f;
        #pragma unroll 8
        for (int k = 0; k < 128; k++) a += dot4(xv[k], w[k]);
        q[h] = a;
      }
      __syncthreads();
      float s0 = 0.f, s1 = 0.f, s2 = 0.f;
      for (int h = tid; h < 512; h += 256) {
        float e = energy_w[h], qq = q[h];
        s0 += tanhf(qq + proj_key[(bb*3+0)*512 + h]) * e;
        s1 += tanhf(qq + proj_key[(bb*3+1)*512 + h]) * e;
        s2 += tanhf(qq + proj_key[(bb*3+2)*512 + h]) * e;
      }
      red3[tid] = s0; red3[256+tid] = s1; red3[512+tid] = s2;
      __syncthreads();
      for (int st = 128; st > 0; st >>= 1) {
        if (tid < st) {
          red3[tid]     += red3[tid+st];
          red3[256+tid] += red3[256+tid+st];
          red3[512+tid] += red3[512+tid+st];
        }
        __syncthreads();
      }
      if (tid == 0) {
        float sc0 = red3[0], sc1 = red3[256], sc2 = red3[512];
        float mx = fmaxf(sc0, fmaxf(sc1, sc2));
        float e0 = expf(sc0-mx), e1 = expf(sc1-mx), e2 = expf(sc2-mx);
        float inv = 1.f/(e0+e1+e2);
        al[0] = e0*inv; al[1] = e1*inv; al[2] = e2*inv;
      }
      __syncthreads();
      for (int a = tid; a < 512; a += 256)
        cv[a] = al[0]*attr_cat[bb*1536 + a] + al[1]*attr_cat[bb*1536 + 512 + a]
              + al[2]*attr_cat[bb*1536 + 1024 + a];
      __syncthreads();
      const float4* cvv = (const float4*)cv;
      float* ctx_next = ctx_all + (t+1)*BB*512;
      for (int h = tid; h < 512; h += 256) {
        const float4* w1 = (const float4*)(ctx_w + (size_t)h*1024);
        const float4* w2 = w1 + 128;
        float a = ctx_b[h];
        #pragma unroll 8
        for (int k = 0; k < 128; k++) { a += dot4(xv[k], w1[k]); a += dot4(cvv[k], w2[k]); }
        ctx_next[bb*512 + h] = tanhf(a);
      }
      __syncthreads();
    }
    gsync(bar);
  }
}

// ---------------- generator GEMM: bf16 MFMA, 128x128 tile, BK=64 (r2-exact) ----------------
__global__ __launch_bounds__(256) void k_gen(const unsigned short* __restrict__ Abf,
    const unsigned short* __restrict__ Bbf, float* __restrict__ out)
{
  __shared__ unsigned short As[128*64];
  __shared__ unsigned short Bs[128*64];
  int tid = threadIdx.x;
  int ntile = blockIdx.x, mtile = blockIdx.y;
  int lane = tid & 63, wave = tid >> 6;
  int quad = lane >> 4, l15 = lane & 15;
  int wm = (wave >> 1) * 64, wn = (wave & 1) * 64;
  int m0 = mtile * 128, n0 = ntile * 128;
  floatx4 acc[4][4] = {};
  for (int kt = 0; kt < 8; kt++) {
    __syncthreads();
    #pragma unroll
    for (int c = 0; c < 4; c++) {
      int f = c*256 + tid;
      int row = f >> 3, k8 = (f & 7) * 8;
      ((short8*)As)[f] = *(const short8*)(Abf + (size_t)(m0 + row)*512 + kt*64 + k8);
      int vr = n0 + row; if (vr > VV-1) vr = VV-1;
      ((short8*)Bs)[f] = *(const short8*)(Bbf + (size_t)vr*512 + kt*64 + k8);
    }
    __syncthreads();
    #pragma unroll
    for (int ks = 0; ks < 2; ks++) {
      short8 af[4], bfr[4];
      #pragma unroll
      for (int i = 0; i < 4; i++)
        af[i] = *(const short8*)&As[(wm + i*16 + l15)*64 + ks*32 + quad*8];
      #pragma unroll
      for (int j = 0; j < 4; j++)
        bfr[j] = *(const short8*)&Bs[(wn + j*16 + l15)*64 + ks*32 + quad*8];
      #pragma unroll
      for (int i = 0; i < 4; i++)
        #pragma unroll
        for (int j = 0; j < 4; j++)
          acc[i][j] = __builtin_amdgcn_mfma_f32_16x16x32_bf16(af[i], bfr[j], acc[i][j], 0, 0, 0);
    }
  }
  #pragma unroll
  for (int i = 0; i < 4; i++) {
    int mbase = m0 + wm + i*16 + quad*4;
    #pragma unroll
    for (int j = 0; j < 4; j++) {
      int v = n0 + wn + j*16 + l15;
      if (v < VV) {
        #pragma unroll
        for (int r = 0; r < 4; r++) {
          int m = mbase + r;
          out[(size_t)((m & 31)*TT + (m >> 5))*VV + v] = acc[i][j][r];
        }
      }
    }
  }
}

// ---------------- in-place row-wise log_softmax over V=30000 ----------------
__global__ __launch_bounds__(256) void k_logsm(float* __restrict__ out)
{
  __shared__ float red[256];
  int row = blockIdx.x, tid = threadIdx.x;
  float* p = out + (size_t)row*VV;
  float4* pv = (float4*)p;
  float m = -1e30f;
  for (int i = tid; i < VV/4; i += 256) {
    float4 v = pv[i];
    m = fmaxf(m, fmaxf(fmaxf(v.x, v.y), fmaxf(v.z, v.w)));
  }
  red[tid] = m; __syncthreads();
  for (int st = 128; st > 0; st >>= 1) { if (tid < st) red[tid] = fmaxf(red[tid], red[tid+st]); __syncthreads(); }
  m = red[0]; __syncthreads();
  float s = 0.f;
  for (int i = tid; i < VV/4; i += 256) {
    float4 v = pv[i];
    s += __expf(v.x-m) + __expf(v.y-m) + __expf(v.z-m) + __expf(v.w-m);
  }
  red[tid] = s; __syncthreads();
  for (int st = 128; st > 0; st >>= 1) { if (tid < st) red[tid] += red[tid+st]; __syncthreads(); }
  float lse = m + logf(red[0]);
  for (int i = tid; i < VV/4; i += 256) {
    float4 v = pv[i];
    v.x -= lse; v.y -= lse; v.z -= lse; v.w -= lse;
    pv[i] = v;
  }
}

extern "C" void kernel_launch(void* const* d_in, const int* in_sizes, int n_in,
                              void* d_out, int out_size, void* d_ws, size_t ws_size,
                              hipStream_t stream)
{
  const int*   user      = (const int*)d_in[0];
  const int*   product   = (const int*)d_in[1];
  const int*   rating    = (const int*)d_in[2];
  const int*   trg       = (const int*)d_in[3];
  const float* embed     = (const float*)d_in[5];
  const float* user_w    = (const float*)d_in[6];
  const float* product_w = (const float*)d_in[7];
  const float* rating_w  = (const float*)d_in[8];
  const float* enc_w     = (const float*)d_in[9];
  const float* enc_b     = (const float*)d_in[10];
  const float* w_ih0     = (const float*)d_in[11];
  const float* w_hh0     = (const float*)d_in[12];
  const float* b_ih0     = (const float*)d_in[13];
  const float* b_hh0     = (const float*)d_in[14];
  const float* w_ih1     = (const float*)d_in[15];
  const float* w_hh1     = (const float*)d_in[16];
  const float* b_ih1     = (const float*)d_in[17];
  const float* b_hh1     = (const float*)d_in[18];
  const float* key_w     = (const float*)d_in[19];
  const float* query_w   = (const float*)d_in[20];
  const float* energy_w  = (const float*)d_in[21];
  const float* ctx_w     = (const float*)d_in[22];
  const float* ctx_b     = (const float*)d_in[23];
  const float* gen_w     = (const float*)d_in[24];
  float* out = (float*)d_out;

  // workspace layout (float units)
  float* ws       = (float*)d_ws;
  float* attr_cat = ws;                     // 49152
  float* proj_key = attr_cat + 49152;       // 49152
  float* h0buf    = proj_key + 49152;       // 32768 (2 slots)
  float* h1buf    = h0buf + 32768;          // 32768
  float* ctx_all  = h1buf + 32768;          // 21*16384 = 344064
  float* gx_all   = ctx_all + 344064;       // 640*1536 = 983040
  unsigned* bar   = (unsigned*)(gx_all + 983040);                 // 2 uints (pad to 8)
  unsigned short* xs_bf   = (unsigned short*)(bar + 8);           // 327680 ushorts
  unsigned short* wih0_bf = xs_bf + 327680;                       // 1572864 ushorts
  unsigned short* genw_bf = wih0_bf + 1572864;                    // 15360000 ushorts
  unsigned short* act_bf  = genw_bf + 15360000;                   // 327680 ushorts

  k_zero<<<1, 64, 0, stream>>>(bar);
  k_cvt<<<7500, 256, 0, stream>>>(gen_w, genw_bf, 1920000);
  k_cvt<<<768, 256, 0, stream>>>(w_ih0, wih0_bf, 196608);
  k_prep<<<1472, 256, 0, stream>>>(user, product, rating, trg, embed, user_w, product_w, rating_w,
                                   attr_cat, xs_bf);
  k_enc<<<128, 256, 0, stream>>>(attr_cat, enc_w, enc_b, h0buf, h1buf, ctx_all);
  k_key<<<192, 256, 0, stream>>>(attr_cat, key_w, proj_key);
  dim3 ggx(12, 5);
  k_gx_mfma<<<ggx, 256, 0, stream>>>(xs_bf, wih0_bf, b_ih0, gx_all);

  k_rec<<<NBLK, 256, 0, stream>>>(gx_all, w_ih0 + 512, w_hh0, b_hh0,
                                  w_ih1, b_ih1, w_hh1, b_hh1,
                                  query_w, energy_w, ctx_w, ctx_b,
                                  proj_key, attr_cat,
                                  h0buf, h1buf, ctx_all, bar);

  k_cvt<<<160, 256, 0, stream>>>(ctx_all + BB*512, act_bf, 40960);
  dim3 ggrid(235, 5);
  k_gen<<<ggrid, 256, 0, stream>>>(act_bf, genw_bf, out);
  k_logsm<<<640, 256, 0, stream>>>(out);
}